// Round 1
// baseline (834.614 us; speedup 1.0000x reference)
//
#include <hip/hip_runtime.h>
#include <stdint.h>

#define BT 4096      // tokens total (8*512)
#define KC 8192      // centroids
#define DD 768       // feature dim
#define T_STRIDE 513 // rep row stride in tokens (we skip token 0 of each batch)

#define BM 64
#define BN 64
#define BK 16
#define NSPLIT 16    // grid.y; each block scans KC/NSPLIT = 512 centroids

// ---------------- kernel 0: row norms (rep tokens + centroids) ----------------
__global__ __launch_bounds__(256) void norms_kernel(
    const float* __restrict__ rep, const float* __restrict__ cent,
    float* __restrict__ norm_rep, float* __restrict__ norm_cent) {
  int wid  = (blockIdx.x * blockDim.x + threadIdx.x) >> 6;
  int lane = threadIdx.x & 63;
  const float* row;
  float* dst;
  if (wid < BT) {
    int b = wid >> 9, tt = wid & 511;
    row = rep + (size_t)(b * T_STRIDE + 1 + tt) * DD;
    dst = norm_rep + wid;
  } else {
    int k = wid - BT;
    if (k >= KC) return;
    row = cent + (size_t)k * DD;
    dst = norm_cent + k;
  }
  float s = 0.f;
  for (int j = lane; j < DD; j += 64) { float v = row[j]; s += v * v; }
  #pragma unroll
  for (int off = 32; off; off >>= 1) s += __shfl_down(s, off, 64);
  if (lane == 0) *dst = s;
}

// ---------------- kernel 1: fused fp32 GEMM + argmin ----------------
__global__ __launch_bounds__(256) void argmin_gemm(
    const float* __restrict__ rep, const float* __restrict__ cent,
    const float* __restrict__ norm_rep, const float* __restrict__ norm_cent,
    unsigned long long* __restrict__ packed) {
  __shared__ float As[BK][BM];  // transposed: As[k][m]
  __shared__ float Bs[BK][BN];  // transposed: Bs[k][n]

  const int tid = threadIdx.x;
  const int m0  = blockIdx.x * BM;
  const int kbase = blockIdx.y * (KC / NSPLIT);
  const int tx = tid & 15;       // centroid group 0..15
  const int ty = tid >> 4;       // token group 0..15

  // staging: each thread loads one float4; row = tid/4 (0..63), col = (tid%4)*4
  const int ldr = tid >> 2;
  const int ldc = (tid & 3) * 4;
  const int t_ld = m0 + ldr;
  const float* arow = rep + (size_t)((t_ld >> 9) * T_STRIDE + 1 + (t_ld & 511)) * DD + ldc;

  unsigned long long best[4];
  #pragma unroll
  for (int i = 0; i < 4; ++i) best[i] = ~0ull;

  float nr[4];
  #pragma unroll
  for (int i = 0; i < 4; ++i) nr[i] = norm_rep[m0 + ty * 4 + i];

  for (int nt = 0; nt < (KC / NSPLIT) / BN; ++nt) {
    const int n0 = kbase + nt * BN;
    const float* brow = cent + (size_t)(n0 + ldr) * DD + ldc;

    float acc[4][4];
    #pragma unroll
    for (int i = 0; i < 4; ++i)
      #pragma unroll
      for (int j = 0; j < 4; ++j) acc[i][j] = 0.f;

    for (int d0 = 0; d0 < DD; d0 += BK) {
      float4 av = *(const float4*)(arow + d0);
      float4 bv = *(const float4*)(brow + d0);
      __syncthreads();  // previous compute done before overwrite
      As[ldc + 0][ldr] = av.x; As[ldc + 1][ldr] = av.y;
      As[ldc + 2][ldr] = av.z; As[ldc + 3][ldr] = av.w;
      Bs[ldc + 0][ldr] = bv.x; Bs[ldc + 1][ldr] = bv.y;
      Bs[ldc + 2][ldr] = bv.z; Bs[ldc + 3][ldr] = bv.w;
      __syncthreads();
      #pragma unroll
      for (int kk = 0; kk < BK; ++kk) {
        float4 a4 = *(const float4*)&As[kk][ty * 4];
        float4 b4 = *(const float4*)&Bs[kk][tx * 4];
        float a[4] = {a4.x, a4.y, a4.z, a4.w};
        float b[4] = {b4.x, b4.y, b4.z, b4.w};
        #pragma unroll
        for (int i = 0; i < 4; ++i)
          #pragma unroll
          for (int j = 0; j < 4; ++j) acc[i][j] += a[i] * b[j];
      }
    }

    // fold this 64-centroid tile into running min
    #pragma unroll
    for (int i = 0; i < 4; ++i) {
      #pragma unroll
      for (int j = 0; j < 4; ++j) {
        int k = n0 + tx * 4 + j;
        float d = (nr[i] + norm_cent[k]) - 2.0f * acc[i][j];  // ref formula order
        unsigned int bits = __float_as_uint(d);
        bits = (bits & 0x80000000u) ? ~bits : (bits | 0x80000000u);  // sortable
        unsigned long long p = ((unsigned long long)bits << 32) | (unsigned int)k;
        if (p < best[i]) best[i] = p;
      }
    }
  }

  // reduce across the 16 tx lanes (same wave: lanes ty*16 .. ty*16+15)
  #pragma unroll
  for (int off = 1; off < 16; off <<= 1) {
    #pragma unroll
    for (int i = 0; i < 4; ++i) {
      unsigned long long o =
          (unsigned long long)__shfl_xor((long long)best[i], off, 64);
      if (o < best[i]) best[i] = o;
    }
  }
  if (tx == 0) {
    #pragma unroll
    for (int i = 0; i < 4; ++i)
      atomicMin(&packed[m0 + ty * 4 + i], best[i]);
  }
}

// ---------------- kernel 2: emit tokens + gather quantized ----------------
__global__ __launch_bounds__(192) void gather_kernel(
    const unsigned long long* __restrict__ packed,
    const float* __restrict__ cent,
    float* __restrict__ out_tokens, float* __restrict__ out_q) {
  int t = blockIdx.x;
  unsigned int k = (unsigned int)(packed[t] & 0xFFFFFFFFull);
  if (threadIdx.x == 0) out_tokens[t] = (float)k;
  const float4* src = (const float4*)(cent + (size_t)k * DD);
  float4* dst = (float4*)(out_q + (size_t)t * DD);
  dst[threadIdx.x] = src[threadIdx.x];  // 192 threads * 4 floats = 768
}

extern "C" void kernel_launch(void* const* d_in, const int* in_sizes, int n_in,
                              void* d_out, int out_size, void* d_ws, size_t ws_size,
                              hipStream_t stream) {
  const float* rep  = (const float*)d_in[0];   // (8,513,768) fp32
  const float* cent = (const float*)d_in[1];   // (8192,768) fp32
  float* out = (float*)d_out;                  // [tokens(4096) | quantized(4096*768)]

  // workspace layout
  unsigned long long* packed = (unsigned long long*)d_ws;            // 4096*8 = 32 KiB
  float* norm_rep  = (float*)((char*)d_ws + 32768);                  // 16 KiB
  float* norm_cent = (float*)((char*)d_ws + 32768 + 16384);          // 32 KiB

  hipMemsetAsync(packed, 0xFF, BT * sizeof(unsigned long long), stream);

  // norms: (4096+8192) waves / 4 waves-per-block = 3072 blocks
  norms_kernel<<<3072, 256, 0, stream>>>(rep, cent, norm_rep, norm_cent);

  dim3 grid(BT / BM, NSPLIT);
  argmin_gemm<<<grid, 256, 0, stream>>>(rep, cent, norm_rep, norm_cent, packed);

  gather_kernel<<<BT, 192, 0, stream>>>(packed, cent, out, out + BT);
}

// Round 2
// 342.303 us; speedup vs baseline: 2.4382x; 2.4382x over previous
//
#include <hip/hip_runtime.h>
#include <stdint.h>

#define BT 4096      // tokens total (8*512)
#define KC 8192      // centroids
#define DD 768       // feature dim
#define T_STRIDE 513 // rep row stride (skip token 0 per batch)

typedef __bf16 bf16x8 __attribute__((ext_vector_type(8)));
typedef float  f32x4  __attribute__((ext_vector_type(4)));

#define GLD16(gp, lp)                                                       \
  __builtin_amdgcn_global_load_lds(                                         \
      (__attribute__((address_space(1))) void*)(gp),                        \
      (__attribute__((address_space(3))) void*)(lp), 16, 0, 0)

// ---------------- kernel 0: row norms (fp32, exact) ----------------
__global__ __launch_bounds__(256) void norms_kernel(
    const float* __restrict__ rep, const float* __restrict__ cent,
    float* __restrict__ norm_rep, float* __restrict__ norm_cent) {
  int wid  = (blockIdx.x * blockDim.x + threadIdx.x) >> 6;
  int lane = threadIdx.x & 63;
  const float* row;
  float* dst;
  if (wid < BT) {
    int b = wid >> 9, tt = wid & 511;
    row = rep + (size_t)(b * T_STRIDE + 1 + tt) * DD;
    dst = norm_rep + wid;
  } else {
    int k = wid - BT;
    if (k >= KC) return;
    row = cent + (size_t)k * DD;
    dst = norm_cent + k;
  }
  float s = 0.f;
  for (int j = lane; j < DD; j += 64) { float v = row[j]; s += v * v; }
  #pragma unroll
  for (int off = 32; off; off >>= 1) s += __shfl_down(s, off, 64);
  if (lane == 0) *dst = s;
}

// ---------------- kernel 1: split fp32 -> bf16 hi/lo ----------------
__global__ __launch_bounds__(256) void split_kernel(
    const float* __restrict__ rep, const float* __restrict__ cent,
    __bf16* __restrict__ a_hi, __bf16* __restrict__ a_lo,
    __bf16* __restrict__ b_hi, __bf16* __restrict__ b_lo) {
  int row = blockIdx.x;
  const float* src;
  __bf16 *hi, *lo;
  if (row < BT) {
    int b = row >> 9, tt = row & 511;
    src = rep + (size_t)(b * T_STRIDE + 1 + tt) * DD;
    hi = a_hi + (size_t)row * DD;
    lo = a_lo + (size_t)row * DD;
  } else {
    int k = row - BT;
    src = cent + (size_t)k * DD;
    hi = b_hi + (size_t)k * DD;
    lo = b_lo + (size_t)k * DD;
  }
  for (int j = threadIdx.x; j < DD; j += 256) {
    float v = src[j];
    __bf16 h = (__bf16)v;
    float r = v - (float)h;
    hi[j] = h;
    lo[j] = (__bf16)r;
  }
}

// ---------------- kernel 2: MFMA GEMM (K=3072 ext) + fused argmin ----------------
// grid: (BT/128, KC/128) = (32, 64); 256 threads (4 waves, 2x2 of 64x64)
__global__ __launch_bounds__(256, 2) void mfma_argmin(
    const __bf16* __restrict__ a_hi, const __bf16* __restrict__ a_lo,
    const __bf16* __restrict__ b_hi, const __bf16* __restrict__ b_lo,
    const float* __restrict__ norm_rep, const float* __restrict__ norm_cent,
    unsigned long long* __restrict__ packed) {
  __shared__ __bf16 As[128 * 32];
  __shared__ __bf16 Bs[128 * 32];

  const int tid = threadIdx.x;
  const int w = tid >> 6, l = tid & 63;
  const int bm0 = blockIdx.x * 128;
  const int bn0 = blockIdx.y * 128;

  // staging geometry: wave-load i covers 16 rows (16 x 64B = 1024B = 64 lanes x 16B)
  const int srow = l >> 2;          // row within 16-row group
  const int scol = (l & 3) * 8;     // bf16 element offset within 32-elem row
  const size_t offA0 = (size_t)(bm0 + (w * 2 + 0) * 16 + srow) * DD + scol;
  const size_t offA1 = (size_t)(bm0 + (w * 2 + 1) * 16 + srow) * DD + scol;
  const size_t offB0 = (size_t)(bn0 + (w * 2 + 0) * 16 + srow) * DD + scol;
  const size_t offB1 = (size_t)(bn0 + (w * 2 + 1) * 16 + srow) * DD + scol;
  __bf16* ldsA0 = As + (w * 2 + 0) * 512;   // uniform base; HW adds lane*16B
  __bf16* ldsA1 = As + (w * 2 + 1) * 512;
  __bf16* ldsB0 = Bs + (w * 2 + 0) * 512;
  __bf16* ldsB1 = Bs + (w * 2 + 1) * 512;

  // compute geometry
  const int wm = (w & 1) * 64, wn = (w >> 1) * 64;
  const int sub = l & 15, q = l >> 4;
  const int aoff = (wm + sub) * 32 + q * 8;  // + mt*16*32
  const int boff = (wn + sub) * 32 + q * 8;  // + nt*16*32

  f32x4 acc[4][4] = {};

  int kin = 0, phase = 0;
  for (int kt = 0; kt < 96; ++kt) {
    const __bf16* abase = (phase < 2) ? a_hi : a_lo;   // A pattern [hi|hi|lo|lo]
    const __bf16* bbase = (phase & 1) ? b_lo : b_hi;   // B pattern [hi|lo|hi|lo]
    __syncthreads();   // previous iter's frag reads done before overwrite
    GLD16(abase + offA0 + kin, ldsA0);
    GLD16(abase + offA1 + kin, ldsA1);
    GLD16(bbase + offB0 + kin, ldsB0);
    GLD16(bbase + offB1 + kin, ldsB1);
    __syncthreads();   // barrier drains vmcnt -> LDS data visible

    bf16x8 af[4], bfr[4];
    #pragma unroll
    for (int i = 0; i < 4; ++i) {
      af[i]  = *(const bf16x8*)(As + aoff + i * 16 * 32);
      bfr[i] = *(const bf16x8*)(Bs + boff + i * 16 * 32);
    }
    #pragma unroll
    for (int mt = 0; mt < 4; ++mt)
      #pragma unroll
      for (int nt = 0; nt < 4; ++nt)
        acc[mt][nt] = __builtin_amdgcn_mfma_f32_16x16x32_bf16(
            af[mt], bfr[nt], acc[mt][nt], 0, 0, 0);

    kin += 32;
    if (kin == DD) { kin = 0; ++phase; }
  }

  // epilogue: dist = nr + nc - 2*dot ; packed sortable argmin
  float ncv[4];
  #pragma unroll
  for (int nt = 0; nt < 4; ++nt) ncv[nt] = norm_cent[bn0 + wn + nt * 16 + sub];

  #pragma unroll
  for (int mt = 0; mt < 4; ++mt) {
    #pragma unroll
    for (int r = 0; r < 4; ++r) {
      const int m = bm0 + wm + mt * 16 + q * 4 + r;
      const float nr = norm_rep[m];
      unsigned long long best = ~0ull;
      #pragma unroll
      for (int nt = 0; nt < 4; ++nt) {
        const int n = bn0 + wn + nt * 16 + sub;
        float d = (nr + ncv[nt]) - 2.0f * acc[mt][nt][r];
        unsigned int bits = __float_as_uint(d);
        bits = (bits & 0x80000000u) ? ~bits : (bits | 0x80000000u);
        unsigned long long p = ((unsigned long long)bits << 32) | (unsigned int)n;
        if (p < best) best = p;
      }
      #pragma unroll
      for (int off = 1; off < 16; off <<= 1) {
        unsigned long long o =
            (unsigned long long)__shfl_xor((long long)best, off, 64);
        if (o < best) best = o;
      }
      if (sub == 0) atomicMin(&packed[m], best);
    }
  }
}

// ---------------- fallback fp32 GEMM+argmin (if ws too small) ----------------
#define FBM 64
#define FBN 64
#define FBK 16
#define FNSPLIT 16
__global__ __launch_bounds__(256) void fp32_argmin_gemm(
    const float* __restrict__ rep, const float* __restrict__ cent,
    const float* __restrict__ norm_rep, const float* __restrict__ norm_cent,
    unsigned long long* __restrict__ packed) {
  __shared__ float Asf[FBK][FBM];
  __shared__ float Bsf[FBK][FBN];
  const int tid = threadIdx.x;
  const int m0  = blockIdx.x * FBM;
  const int kbase = blockIdx.y * (KC / FNSPLIT);
  const int tx = tid & 15, ty = tid >> 4;
  const int ldr = tid >> 2, ldc = (tid & 3) * 4;
  const int t_ld = m0 + ldr;
  const float* arow =
      rep + (size_t)((t_ld >> 9) * T_STRIDE + 1 + (t_ld & 511)) * DD + ldc;
  unsigned long long best[4];
  #pragma unroll
  for (int i = 0; i < 4; ++i) best[i] = ~0ull;
  float nr[4];
  #pragma unroll
  for (int i = 0; i < 4; ++i) nr[i] = norm_rep[m0 + ty * 4 + i];
  for (int nt = 0; nt < (KC / FNSPLIT) / FBN; ++nt) {
    const int n0 = kbase + nt * FBN;
    const float* brow = cent + (size_t)(n0 + ldr) * DD + ldc;
    float acc[4][4];
    #pragma unroll
    for (int i = 0; i < 4; ++i)
      #pragma unroll
      for (int j = 0; j < 4; ++j) acc[i][j] = 0.f;
    for (int d0 = 0; d0 < DD; d0 += FBK) {
      float4 av = *(const float4*)(arow + d0);
      float4 bv = *(const float4*)(brow + d0);
      __syncthreads();
      Asf[ldc + 0][ldr] = av.x; Asf[ldc + 1][ldr] = av.y;
      Asf[ldc + 2][ldr] = av.z; Asf[ldc + 3][ldr] = av.w;
      Bsf[ldc + 0][ldr] = bv.x; Bsf[ldc + 1][ldr] = bv.y;
      Bsf[ldc + 2][ldr] = bv.z; Bsf[ldc + 3][ldr] = bv.w;
      __syncthreads();
      #pragma unroll
      for (int kk = 0; kk < FBK; ++kk) {
        float4 a4 = *(const float4*)&Asf[kk][ty * 4];
        float4 b4 = *(const float4*)&Bsf[kk][tx * 4];
        float a[4] = {a4.x, a4.y, a4.z, a4.w};
        float b[4] = {b4.x, b4.y, b4.z, b4.w};
        #pragma unroll
        for (int i = 0; i < 4; ++i)
          #pragma unroll
          for (int j = 0; j < 4; ++j) acc[i][j] += a[i] * b[j];
      }
    }
    #pragma unroll
    for (int i = 0; i < 4; ++i) {
      #pragma unroll
      for (int j = 0; j < 4; ++j) {
        int k = n0 + tx * 4 + j;
        float d = (nr[i] + norm_cent[k]) - 2.0f * acc[i][j];
        unsigned int bits = __float_as_uint(d);
        bits = (bits & 0x80000000u) ? ~bits : (bits | 0x80000000u);
        unsigned long long p = ((unsigned long long)bits << 32) | (unsigned int)k;
        if (p < best[i]) best[i] = p;
      }
    }
  }
  #pragma unroll
  for (int off = 1; off < 16; off <<= 1) {
    #pragma unroll
    for (int i = 0; i < 4; ++i) {
      unsigned long long o =
          (unsigned long long)__shfl_xor((long long)best[i], off, 64);
      if (o < best[i]) best[i] = o;
    }
  }
  if (tx == 0) {
    #pragma unroll
    for (int i = 0; i < 4; ++i)
      atomicMin(&packed[m0 + ty * 4 + i], best[i]);
  }
}

// ---------------- kernel 3: emit tokens + gather ----------------
__global__ __launch_bounds__(192) void gather_kernel(
    const unsigned long long* __restrict__ packed,
    const float* __restrict__ cent,
    float* __restrict__ out_tokens, float* __restrict__ out_q) {
  int t = blockIdx.x;
  unsigned int k = (unsigned int)(packed[t] & 0xFFFFFFFFull);
  if (threadIdx.x == 0) out_tokens[t] = (float)k;
  const float4* src = (const float4*)(cent + (size_t)k * DD);
  float4* dst = (float4*)(out_q + (size_t)t * DD);
  dst[threadIdx.x] = src[threadIdx.x];
}

extern "C" void kernel_launch(void* const* d_in, const int* in_sizes, int n_in,
                              void* d_out, int out_size, void* d_ws, size_t ws_size,
                              hipStream_t stream) {
  const float* rep  = (const float*)d_in[0];   // (8,513,768) fp32
  const float* cent = (const float*)d_in[1];   // (8192,768) fp32
  float* out = (float*)d_out;                  // [tokens(4096) | quantized(4096*768)]

  // workspace layout
  unsigned long long* packed = (unsigned long long*)d_ws;        // 32 KiB @ 0
  float* norm_rep  = (float*)((char*)d_ws + 32768);              // 16 KiB
  float* norm_cent = (float*)((char*)d_ws + 49152);              // 32 KiB
  __bf16* a_hi = (__bf16*)((char*)d_ws + 81920);                 // 6 MiB
  __bf16* a_lo = (__bf16*)((char*)d_ws + 81920 + 6291456);
  __bf16* b_hi = (__bf16*)((char*)d_ws + 81920 + 2 * 6291456);  // 12 MiB
  __bf16* b_lo = (__bf16*)((char*)d_ws + 81920 + 2 * 6291456 + 12582912);
  const size_t REQUIRED_WS = 81920ull + 2 * 6291456ull + 2 * 12582912ull;

  hipMemsetAsync(packed, 0xFF, BT * sizeof(unsigned long long), stream);
  norms_kernel<<<3072, 256, 0, stream>>>(rep, cent, norm_rep, norm_cent);

  if (ws_size >= REQUIRED_WS) {
    split_kernel<<<BT + KC, 256, 0, stream>>>(rep, cent, a_hi, a_lo, b_hi, b_lo);
    dim3 grid(BT / 128, KC / 128);
    mfma_argmin<<<grid, 256, 0, stream>>>(a_hi, a_lo, b_hi, b_lo,
                                          norm_rep, norm_cent, packed);
  } else {
    dim3 grid(BT / FBM, FNSPLIT);
    fp32_argmin_gemm<<<grid, 256, 0, stream>>>(rep, cent, norm_rep, norm_cent,
                                               packed);
  }

  gather_kernel<<<BT, 192, 0, stream>>>(packed, cent, out, out + BT);
}

// Round 3
// 295.213 us; speedup vs baseline: 2.8272x; 1.1595x over previous
//
#include <hip/hip_runtime.h>
#include <stdint.h>

#define BT 4096      // tokens total (8*512)
#define KC 8192      // centroids
#define DD 768       // feature dim
#define T_STRIDE 513 // rep row stride (skip token 0 per batch)

typedef _Float16 f16x8 __attribute__((ext_vector_type(8)));
typedef float    f32x4 __attribute__((ext_vector_type(4)));

#define GLD16(gp, lp)                                                       \
  __builtin_amdgcn_global_load_lds(                                         \
      (__attribute__((address_space(1))) void*)(gp),                        \
      (__attribute__((address_space(3))) void*)(lp), 16, 0, 0)

// ------- kernel 0: fused split fp32 -> fp16 hi + scaled-lo, + exact fp32 norms -------
// one wave per row; residual scaled by 2^11 to stay in fp16 normal range
__global__ __launch_bounds__(256) void split_norm_kernel(
    const float* __restrict__ rep, const float* __restrict__ cent,
    _Float16* __restrict__ a_hi, _Float16* __restrict__ a_lo,
    _Float16* __restrict__ b_hi, _Float16* __restrict__ b_lo,
    float* __restrict__ norm_rep, float* __restrict__ norm_cent) {
  int wid  = (blockIdx.x * blockDim.x + threadIdx.x) >> 6;
  int lane = threadIdx.x & 63;
  const float* src;
  _Float16 *hi, *lo;
  float* nd;
  if (wid < BT) {
    int b = wid >> 9, tt = wid & 511;
    src = rep + (size_t)(b * T_STRIDE + 1 + tt) * DD;
    hi = a_hi + (size_t)wid * DD;
    lo = a_lo + (size_t)wid * DD;
    nd = norm_rep + wid;
  } else {
    int k = wid - BT;
    if (k >= KC) return;
    src = cent + (size_t)k * DD;
    hi = b_hi + (size_t)k * DD;
    lo = b_lo + (size_t)k * DD;
    nd = norm_cent + k;
  }
  float s = 0.f;
  #pragma unroll
  for (int jj = 0; jj < DD / 64; ++jj) {
    int j = jj * 64 + lane;
    float v = src[j];
    s += v * v;
    _Float16 h = (_Float16)v;              // RTN
    float r = (v - (float)h) * 2048.0f;    // exact (Sterbenz + pow2 scale)
    hi[j] = h;
    lo[j] = (_Float16)r;
  }
  #pragma unroll
  for (int off = 32; off; off >>= 1) s += __shfl_down(s, off, 64);
  if (lane == 0) *nd = s;
}

// ------- kernel 1: MFMA GEMM (K=2304 ext, 3 phases) + fused argmin -------
// grid: (BT/128, KC/128) = (32, 64); 256 threads (4 waves, 2x2 of 64x64)
__global__ __launch_bounds__(256, 2) void mfma_argmin(
    const _Float16* __restrict__ a_hi, const _Float16* __restrict__ a_lo,
    const _Float16* __restrict__ b_hi, const _Float16* __restrict__ b_lo,
    const float* __restrict__ norm_rep, const float* __restrict__ norm_cent,
    unsigned long long* __restrict__ packed) {
  __shared__ _Float16 As[128 * 32];
  __shared__ _Float16 Bs[128 * 32];

  const int tid = threadIdx.x;
  const int w = tid >> 6, l = tid & 63;
  const int bm0 = blockIdx.x * 128;
  const int bn0 = blockIdx.y * 128;

  // staging: each wave covers 16 rows (16 x 64B = 1024B = 64 lanes x 16B)
  const int srow = l >> 2;
  const int scol = (l & 3) * 8;
  const size_t offA0 = (size_t)(bm0 + (w * 2 + 0) * 16 + srow) * DD + scol;
  const size_t offA1 = (size_t)(bm0 + (w * 2 + 1) * 16 + srow) * DD + scol;
  const size_t offB0 = (size_t)(bn0 + (w * 2 + 0) * 16 + srow) * DD + scol;
  const size_t offB1 = (size_t)(bn0 + (w * 2 + 1) * 16 + srow) * DD + scol;
  _Float16* ldsA0 = As + (w * 2 + 0) * 512;
  _Float16* ldsA1 = As + (w * 2 + 1) * 512;
  _Float16* ldsB0 = Bs + (w * 2 + 0) * 512;
  _Float16* ldsB1 = Bs + (w * 2 + 1) * 512;

  // compute geometry: each wave owns a 64x64 quadrant
  const int wm = (w & 1) * 64, wn = (w >> 1) * 64;
  const int sub = l & 15, q = l >> 4;
  const int aoff = (wm + sub) * 32 + q * 8;
  const int boff = (wn + sub) * 32 + q * 8;

  f32x4 acc[4][4] = {};

  // phase 0: lo_s . b_hi   (scaled 2^11)
  // phase 1: hi   . b_lo_s (scaled 2^11)  -> then rescale acc by 2^-11
  // phase 2: hi   . b_hi
  const _Float16* APH[3] = {a_lo, a_hi, a_hi};
  const _Float16* BPH[3] = {b_hi, b_lo, b_hi};

  #pragma unroll
  for (int phase = 0; phase < 3; ++phase) {
    const _Float16* ab = APH[phase];
    const _Float16* bb = BPH[phase];
    for (int kin = 0; kin < DD; kin += 32) {
      __syncthreads();   // previous iter's frag reads done before overwrite
      GLD16(ab + offA0 + kin, ldsA0);
      GLD16(ab + offA1 + kin, ldsA1);
      GLD16(bb + offB0 + kin, ldsB0);
      GLD16(bb + offB1 + kin, ldsB1);
      __syncthreads();   // barrier drains vmcnt -> LDS data visible

      f16x8 af[4], bfr[4];
      #pragma unroll
      for (int i = 0; i < 4; ++i) {
        af[i]  = *(const f16x8*)(As + aoff + i * 16 * 32);
        bfr[i] = *(const f16x8*)(Bs + boff + i * 16 * 32);
      }
      #pragma unroll
      for (int mt = 0; mt < 4; ++mt)
        #pragma unroll
        for (int nt = 0; nt < 4; ++nt)
          acc[mt][nt] = __builtin_amdgcn_mfma_f32_16x16x32_f16(
              af[mt], bfr[nt], acc[mt][nt], 0, 0, 0);
    }
    if (phase == 1) {
      // both scaled mixed terms accumulated -> undo the 2^11 (exact)
      #pragma unroll
      for (int mt = 0; mt < 4; ++mt)
        #pragma unroll
        for (int nt = 0; nt < 4; ++nt)
          acc[mt][nt] *= (1.0f / 2048.0f);
    }
  }

  // epilogue: dist = nr + nc - 2*dot ; packed sortable argmin
  float ncv[4];
  #pragma unroll
  for (int nt = 0; nt < 4; ++nt) ncv[nt] = norm_cent[bn0 + wn + nt * 16 + sub];

  #pragma unroll
  for (int mt = 0; mt < 4; ++mt) {
    #pragma unroll
    for (int r = 0; r < 4; ++r) {
      const int m = bm0 + wm + mt * 16 + q * 4 + r;
      const float nr = norm_rep[m];
      unsigned long long best = ~0ull;
      #pragma unroll
      for (int nt = 0; nt < 4; ++nt) {
        const int n = bn0 + wn + nt * 16 + sub;
        float d = (nr + ncv[nt]) - 2.0f * acc[mt][nt][r];
        unsigned int bits = __float_as_uint(d);
        bits = (bits & 0x80000000u) ? ~bits : (bits | 0x80000000u);
        unsigned long long p = ((unsigned long long)bits << 32) | (unsigned int)n;
        if (p < best) best = p;
      }
      #pragma unroll
      for (int off = 1; off < 16; off <<= 1) {
        unsigned long long o =
            (unsigned long long)__shfl_xor((long long)best, off, 64);
        if (o < best) best = o;
      }
      if (sub == 0) atomicMin(&packed[m], best);
    }
  }
}

// ---------------- fallback fp32 GEMM+argmin (if ws too small) ----------------
#define FBM 64
#define FBN 64
#define FBK 16
#define FNSPLIT 16
__global__ __launch_bounds__(256) void fp32_argmin_gemm(
    const float* __restrict__ rep, const float* __restrict__ cent,
    const float* __restrict__ norm_rep, const float* __restrict__ norm_cent,
    unsigned long long* __restrict__ packed) {
  __shared__ float Asf[FBK][FBM];
  __shared__ float Bsf[FBK][FBN];
  const int tid = threadIdx.x;
  const int m0  = blockIdx.x * FBM;
  const int kbase = blockIdx.y * (KC / FNSPLIT);
  const int tx = tid & 15, ty = tid >> 4;
  const int ldr = tid >> 2, ldc = (tid & 3) * 4;
  const int t_ld = m0 + ldr;
  const float* arow =
      rep + (size_t)((t_ld >> 9) * T_STRIDE + 1 + (t_ld & 511)) * DD + ldc;
  unsigned long long best[4];
  #pragma unroll
  for (int i = 0; i < 4; ++i) best[i] = ~0ull;
  float nr[4];
  #pragma unroll
  for (int i = 0; i < 4; ++i) nr[i] = norm_rep[m0 + ty * 4 + i];
  for (int nt = 0; nt < (KC / FNSPLIT) / FBN; ++nt) {
    const int n0 = kbase + nt * FBN;
    const float* brow = cent + (size_t)(n0 + ldr) * DD + ldc;
    float acc[4][4];
    #pragma unroll
    for (int i = 0; i < 4; ++i)
      #pragma unroll
      for (int j = 0; j < 4; ++j) acc[i][j] = 0.f;
    for (int d0 = 0; d0 < DD; d0 += FBK) {
      float4 av = *(const float4*)(arow + d0);
      float4 bv = *(const float4*)(brow + d0);
      __syncthreads();
      Asf[ldc + 0][ldr] = av.x; Asf[ldc + 1][ldr] = av.y;
      Asf[ldc + 2][ldr] = av.z; Asf[ldc + 3][ldr] = av.w;
      Bsf[ldc + 0][ldr] = bv.x; Bsf[ldc + 1][ldr] = bv.y;
      Bsf[ldc + 2][ldr] = bv.z; Bsf[ldc + 3][ldr] = bv.w;
      __syncthreads();
      #pragma unroll
      for (int kk = 0; kk < FBK; ++kk) {
        float4 a4 = *(const float4*)&Asf[kk][ty * 4];
        float4 b4 = *(const float4*)&Bsf[kk][tx * 4];
        float a[4] = {a4.x, a4.y, a4.z, a4.w};
        float b[4] = {b4.x, b4.y, b4.z, b4.w};
        #pragma unroll
        for (int i = 0; i < 4; ++i)
          #pragma unroll
          for (int j = 0; j < 4; ++j) acc[i][j] += a[i] * b[j];
      }
    }
    #pragma unroll
    for (int i = 0; i < 4; ++i) {
      #pragma unroll
      for (int j = 0; j < 4; ++j) {
        int k = n0 + tx * 4 + j;
        float d = (nr[i] + norm_cent[k]) - 2.0f * acc[i][j];
        unsigned int bits = __float_as_uint(d);
        bits = (bits & 0x80000000u) ? ~bits : (bits | 0x80000000u);
        unsigned long long p = ((unsigned long long)bits << 32) | (unsigned int)k;
        if (p < best[i]) best[i] = p;
      }
    }
  }
  #pragma unroll
  for (int off = 1; off < 16; off <<= 1) {
    #pragma unroll
    for (int i = 0; i < 4; ++i) {
      unsigned long long o =
          (unsigned long long)__shfl_xor((long long)best[i], off, 64);
      if (o < best[i]) best[i] = o;
    }
  }
  if (tx == 0) {
    #pragma unroll
    for (int i = 0; i < 4; ++i)
      atomicMin(&packed[m0 + ty * 4 + i], best[i]);
  }
}

// ---------------- kernel 2: emit tokens + gather ----------------
__global__ __launch_bounds__(192) void gather_kernel(
    const unsigned long long* __restrict__ packed,
    const float* __restrict__ cent,
    float* __restrict__ out_tokens, float* __restrict__ out_q) {
  int t = blockIdx.x;
  unsigned int k = (unsigned int)(packed[t] & 0xFFFFFFFFull);
  if (threadIdx.x == 0) out_tokens[t] = (float)k;
  const float4* src = (const float4*)(cent + (size_t)k * DD);
  float4* dst = (float4*)(out_q + (size_t)t * DD);
  dst[threadIdx.x] = src[threadIdx.x];
}

extern "C" void kernel_launch(void* const* d_in, const int* in_sizes, int n_in,
                              void* d_out, int out_size, void* d_ws, size_t ws_size,
                              hipStream_t stream) {
  const float* rep  = (const float*)d_in[0];   // (8,513,768) fp32
  const float* cent = (const float*)d_in[1];   // (8192,768) fp32
  float* out = (float*)d_out;                  // [tokens(4096) | quantized(4096*768)]

  // workspace layout
  unsigned long long* packed = (unsigned long long*)d_ws;        // 32 KiB @ 0
  float* norm_rep  = (float*)((char*)d_ws + 32768);              // 16 KiB
  float* norm_cent = (float*)((char*)d_ws + 49152);              // 32 KiB
  _Float16* a_hi = (_Float16*)((char*)d_ws + 81920);             // 6 MiB
  _Float16* a_lo = (_Float16*)((char*)d_ws + 81920 + 6291456);
  _Float16* b_hi = (_Float16*)((char*)d_ws + 81920 + 2 * 6291456);  // 12 MiB
  _Float16* b_lo = (_Float16*)((char*)d_ws + 81920 + 2 * 6291456 + 12582912);
  const size_t REQUIRED_WS = 81920ull + 2 * 6291456ull + 2 * 12582912ull;

  hipMemsetAsync(packed, 0xFF, BT * sizeof(unsigned long long), stream);

  if (ws_size >= REQUIRED_WS) {
    // (4096+8192) rows, one wave each, 4 waves/block -> 3072 blocks
    split_norm_kernel<<<3072, 256, 0, stream>>>(rep, cent, a_hi, a_lo, b_hi,
                                                b_lo, norm_rep, norm_cent);
    dim3 grid(BT / 128, KC / 128);
    mfma_argmin<<<grid, 256, 0, stream>>>(a_hi, a_lo, b_hi, b_lo,
                                          norm_rep, norm_cent, packed);
  } else {
    // fp32 fallback needs only norms
    split_norm_kernel<<<3072, 256, 0, stream>>>(rep, cent, nullptr, nullptr,
                                                nullptr, nullptr, norm_rep,
                                                norm_cent);  // unreachable path
    dim3 grid(BT / FBM, FNSPLIT);
    fp32_argmin_gemm<<<grid, 256, 0, stream>>>(rep, cent, norm_rep, norm_cent,
                                               packed);
  }

  gather_kernel<<<BT, 192, 0, stream>>>(packed, cent, out, out + BT);
}

// Round 4
// 174.316 us; speedup vs baseline: 4.7879x; 1.6935x over previous
//
#include <hip/hip_runtime.h>
#include <stdint.h>

#define BT 4096      // tokens total (8*512)
#define KC 8192      // centroids
#define DD 768       // feature dim
#define T_STRIDE 513 // rep row stride (skip token 0 per batch)

typedef _Float16 f16x8 __attribute__((ext_vector_type(8)));
typedef _Float16 f16x4 __attribute__((ext_vector_type(4)));
typedef float    f32x4 __attribute__((ext_vector_type(4)));

#define GLD16(gp, lp)                                                       \
  __builtin_amdgcn_global_load_lds(                                         \
      (__attribute__((address_space(1))) void*)(gp),                        \
      (__attribute__((address_space(3))) void*)(lp), 16, 0, 0)

__device__ __forceinline__ unsigned int sortable_bits(float d) {
  unsigned int bits = __float_as_uint(d);
  return (bits & 0x80000000u) ? ~bits : (bits | 0x80000000u);
}

// ------- kernel 0: split fp32 -> fp16 hi (+optional scaled-lo) + exact fp32 norms -------
__global__ __launch_bounds__(256) void split_norm_kernel(
    const float* __restrict__ rep, const float* __restrict__ cent,
    _Float16* __restrict__ a_hi, _Float16* __restrict__ a_lo,
    _Float16* __restrict__ b_hi, _Float16* __restrict__ b_lo,
    float* __restrict__ norm_rep, float* __restrict__ norm_cent) {
  int wid  = (blockIdx.x * blockDim.x + threadIdx.x) >> 6;
  int lane = threadIdx.x & 63;
  const float* src;
  _Float16 *hi, *lo;
  float* nd;
  if (wid < BT) {
    int b = wid >> 9, tt = wid & 511;
    src = rep + (size_t)(b * T_STRIDE + 1 + tt) * DD;
    hi = a_hi ? a_hi + (size_t)wid * DD : nullptr;
    lo = a_lo ? a_lo + (size_t)wid * DD : nullptr;
    nd = norm_rep + wid;
  } else {
    int k = wid - BT;
    if (k >= KC) return;
    src = cent + (size_t)k * DD;
    hi = b_hi ? b_hi + (size_t)k * DD : nullptr;
    lo = b_lo ? b_lo + (size_t)k * DD : nullptr;
    nd = norm_cent + k;
  }
  float s = 0.f;
  #pragma unroll
  for (int jj = 0; jj < DD / 64; ++jj) {
    int j = jj * 64 + lane;
    float v = src[j];
    s += v * v;
    _Float16 h = (_Float16)v;              // RTN
    if (hi) hi[j] = h;
    if (lo) lo[j] = (_Float16)((v - (float)h) * 2048.0f);  // exact residual, scaled
  }
  #pragma unroll
  for (int off = 32; off; off >>= 1) s += __shfl_down(s, off, 64);
  if (lane == 0) *nd = s;
}

// ------- kernel A1: hi.hi MFMA GEMM (K=768) -> approx distances (fp16) -------
// grid: (BT/128, KC/128) = (32, 64); 256 threads (4 waves, 2x2 of 64x64)
__global__ __launch_bounds__(256, 2) void mfma_dist(
    const _Float16* __restrict__ a_hi, const _Float16* __restrict__ b_hi,
    const float* __restrict__ norm_rep, const float* __restrict__ norm_cent,
    _Float16* __restrict__ Dst) {
  __shared__ _Float16 As[128 * 32];
  __shared__ _Float16 Bs[128 * 32];

  const int tid = threadIdx.x;
  const int w = tid >> 6, l = tid & 63;
  const int bm0 = blockIdx.x * 128;
  const int bn0 = blockIdx.y * 128;

  const int srow = l >> 2;
  const int scol = (l & 3) * 8;
  const size_t offA0 = (size_t)(bm0 + (w * 2 + 0) * 16 + srow) * DD + scol;
  const size_t offA1 = (size_t)(bm0 + (w * 2 + 1) * 16 + srow) * DD + scol;
  const size_t offB0 = (size_t)(bn0 + (w * 2 + 0) * 16 + srow) * DD + scol;
  const size_t offB1 = (size_t)(bn0 + (w * 2 + 1) * 16 + srow) * DD + scol;
  _Float16* ldsA0 = As + (w * 2 + 0) * 512;
  _Float16* ldsA1 = As + (w * 2 + 1) * 512;
  _Float16* ldsB0 = Bs + (w * 2 + 0) * 512;
  _Float16* ldsB1 = Bs + (w * 2 + 1) * 512;

  const int wm = (w & 1) * 64, wn = (w >> 1) * 64;
  const int sub = l & 15, q = l >> 4;
  const int aoff = (wm + sub) * 32 + q * 8;
  const int boff = (wn + sub) * 32 + q * 8;

  f32x4 acc[4][4] = {};

  for (int kin = 0; kin < DD; kin += 32) {
    __syncthreads();
    GLD16(a_hi + offA0 + kin, ldsA0);
    GLD16(a_hi + offA1 + kin, ldsA1);
    GLD16(b_hi + offB0 + kin, ldsB0);
    GLD16(b_hi + offB1 + kin, ldsB1);
    __syncthreads();

    f16x8 af[4], bfr[4];
    #pragma unroll
    for (int i = 0; i < 4; ++i) {
      af[i]  = *(const f16x8*)(As + aoff + i * 16 * 32);
      bfr[i] = *(const f16x8*)(Bs + boff + i * 16 * 32);
    }
    #pragma unroll
    for (int mt = 0; mt < 4; ++mt)
      #pragma unroll
      for (int nt = 0; nt < 4; ++nt)
        acc[mt][nt] = __builtin_amdgcn_mfma_f32_16x16x32_f16(
            af[mt], bfr[nt], acc[mt][nt], 0, 0, 0);
  }

  // epilogue: d = nr + nc - 2*dot -> fp16 store
  float ncv[4];
  #pragma unroll
  for (int nt = 0; nt < 4; ++nt) ncv[nt] = norm_cent[bn0 + wn + nt * 16 + sub];

  #pragma unroll
  for (int mt = 0; mt < 4; ++mt) {
    #pragma unroll
    for (int r = 0; r < 4; ++r) {
      const int m = bm0 + wm + mt * 16 + q * 4 + r;
      const float nr = norm_rep[m];
      #pragma unroll
      for (int nt = 0; nt < 4; ++nt) {
        const int n = bn0 + wn + nt * 16 + sub;
        float d = (nr + ncv[nt]) - 2.0f * acc[mt][nt][r];
        Dst[(size_t)m * KC + n] = (_Float16)d;
      }
    }
  }
}

// ------- kernel A2: per-token refine (min scan + exact fp32 recheck) -------
// |d_true - d_stored| <= 1.2 (fp16 split + mfma rounding) + 0.5 (fp16 store);
// candidate window 6.0 gives >2.5x margin over the worst-case chain (3.4).
#define MAXC 128
__global__ __launch_bounds__(256) void refine_kernel(
    const _Float16* __restrict__ D, const float* __restrict__ rep,
    const float* __restrict__ cent, const float* __restrict__ norm_rep,
    const float* __restrict__ norm_cent,
    float* __restrict__ out_tokens, float* __restrict__ out_q) {
  __shared__ unsigned long long s_best[4];
  __shared__ float s_red[4];
  __shared__ int s_cand[MAXC];
  __shared__ int s_cnt;
  __shared__ float s_dmin;
  __shared__ int s_kbest;

  const int t = blockIdx.x;
  const int tid = threadIdx.x;
  const int w = tid >> 6, l = tid & 63;
  const _Float16* drow = D + (size_t)t * KC;

  // pass 1: load 32 entries/thread (f16x4 vector loads), track packed min
  float dloc[32];
  unsigned long long best = ~0ull;
  #pragma unroll
  for (int j = 0; j < 8; ++j) {
    const int k0 = j * 1024 + tid * 4;
    f16x4 v = *(const f16x4*)(drow + k0);
    #pragma unroll
    for (int e = 0; e < 4; ++e) {
      float d = (float)v[e];
      dloc[j * 4 + e] = d;
      unsigned long long p =
          ((unsigned long long)sortable_bits(d) << 32) | (unsigned)(k0 + e);
      if (p < best) best = p;
    }
  }
  #pragma unroll
  for (int off = 32; off; off >>= 1) {
    unsigned long long o = (unsigned long long)__shfl_xor((long long)best, off, 64);
    if (o < best) best = o;
  }
  if (l == 0) s_best[w] = best;
  if (tid == 0) s_cnt = 0;
  __syncthreads();
  if (tid == 0) {
    unsigned long long b = s_best[0];
    #pragma unroll
    for (int i = 1; i < 4; ++i) if (s_best[i] < b) b = s_best[i];
    unsigned int sb = (unsigned int)(b >> 32);
    unsigned int orig = (sb & 0x80000000u) ? (sb ^ 0x80000000u) : ~sb;
    s_dmin = __uint_as_float(orig);
  }
  __syncthreads();

  // pass 2: collect candidates within window
  const float thresh = s_dmin + 6.0f;
  #pragma unroll
  for (int j = 0; j < 8; ++j) {
    const int k0 = j * 1024 + tid * 4;
    #pragma unroll
    for (int e = 0; e < 4; ++e) {
      if (dloc[j * 4 + e] <= thresh) {
        int idx = atomicAdd(&s_cnt, 1);
        if (idx < MAXC) s_cand[idx] = k0 + e;
      }
    }
  }
  __syncthreads();
  const int cnt = (s_cnt < MAXC) ? s_cnt : MAXC;

  // pass 3: exact fp32 recompute of each candidate
  const int b_ = t >> 9, tt = t & 511;
  const float* rrow = rep + (size_t)(b_ * T_STRIDE + 1 + tt) * DD;
  const float nr = norm_rep[t];
  unsigned long long bestE = ~0ull;
  for (int c = 0; c < cnt; ++c) {
    const int k = s_cand[c];
    const float* crow = cent + (size_t)k * DD;
    float part = 0.f;
    #pragma unroll
    for (int j = 0; j < 3; ++j)
      part += rrow[tid + j * 256] * crow[tid + j * 256];
    #pragma unroll
    for (int off = 32; off; off >>= 1) part += __shfl_down(part, off, 64);
    if (l == 0) s_red[w] = part;
    __syncthreads();
    if (tid == 0) {
      float dot = s_red[0] + s_red[1] + s_red[2] + s_red[3];
      float d = (nr + norm_cent[k]) - 2.0f * dot;
      unsigned long long p =
          ((unsigned long long)sortable_bits(d) << 32) | (unsigned)k;
      if (p < bestE) bestE = p;
    }
    __syncthreads();
  }
  if (tid == 0) {
    s_kbest = (int)(bestE & 0xFFFFFFFFull);
    out_tokens[t] = (float)s_kbest;
  }
  __syncthreads();
  const int kbest = s_kbest;
  if (tid < 192) {
    const float4* src = (const float4*)(cent + (size_t)kbest * DD);
    float4* dst = (float4*)(out_q + (size_t)t * DD);
    dst[tid] = src[tid];
  }
}

// ------- fallback path B: round-3 3-phase exact fp16-split GEMM + argmin -------
__global__ __launch_bounds__(256, 2) void mfma_argmin(
    const _Float16* __restrict__ a_hi, const _Float16* __restrict__ a_lo,
    const _Float16* __restrict__ b_hi, const _Float16* __restrict__ b_lo,
    const float* __restrict__ norm_rep, const float* __restrict__ norm_cent,
    unsigned long long* __restrict__ packed) {
  __shared__ _Float16 As[128 * 32];
  __shared__ _Float16 Bs[128 * 32];

  const int tid = threadIdx.x;
  const int w = tid >> 6, l = tid & 63;
  const int bm0 = blockIdx.x * 128;
  const int bn0 = blockIdx.y * 128;

  const int srow = l >> 2;
  const int scol = (l & 3) * 8;
  const size_t offA0 = (size_t)(bm0 + (w * 2 + 0) * 16 + srow) * DD + scol;
  const size_t offA1 = (size_t)(bm0 + (w * 2 + 1) * 16 + srow) * DD + scol;
  const size_t offB0 = (size_t)(bn0 + (w * 2 + 0) * 16 + srow) * DD + scol;
  const size_t offB1 = (size_t)(bn0 + (w * 2 + 1) * 16 + srow) * DD + scol;
  _Float16* ldsA0 = As + (w * 2 + 0) * 512;
  _Float16* ldsA1 = As + (w * 2 + 1) * 512;
  _Float16* ldsB0 = Bs + (w * 2 + 0) * 512;
  _Float16* ldsB1 = Bs + (w * 2 + 1) * 512;

  const int wm = (w & 1) * 64, wn = (w >> 1) * 64;
  const int sub = l & 15, q = l >> 4;
  const int aoff = (wm + sub) * 32 + q * 8;
  const int boff = (wn + sub) * 32 + q * 8;

  f32x4 acc[4][4] = {};
  const _Float16* APH[3] = {a_lo, a_hi, a_hi};
  const _Float16* BPH[3] = {b_hi, b_lo, b_hi};

  #pragma unroll
  for (int phase = 0; phase < 3; ++phase) {
    const _Float16* ab = APH[phase];
    const _Float16* bb = BPH[phase];
    for (int kin = 0; kin < DD; kin += 32) {
      __syncthreads();
      GLD16(ab + offA0 + kin, ldsA0);
      GLD16(ab + offA1 + kin, ldsA1);
      GLD16(bb + offB0 + kin, ldsB0);
      GLD16(bb + offB1 + kin, ldsB1);
      __syncthreads();

      f16x8 af[4], bfr[4];
      #pragma unroll
      for (int i = 0; i < 4; ++i) {
        af[i]  = *(const f16x8*)(As + aoff + i * 16 * 32);
        bfr[i] = *(const f16x8*)(Bs + boff + i * 16 * 32);
      }
      #pragma unroll
      for (int mt = 0; mt < 4; ++mt)
        #pragma unroll
        for (int nt = 0; nt < 4; ++nt)
          acc[mt][nt] = __builtin_amdgcn_mfma_f32_16x16x32_f16(
              af[mt], bfr[nt], acc[mt][nt], 0, 0, 0);
    }
    if (phase == 1) {
      #pragma unroll
      for (int mt = 0; mt < 4; ++mt)
        #pragma unroll
        for (int nt = 0; nt < 4; ++nt)
          acc[mt][nt] *= (1.0f / 2048.0f);
    }
  }

  float ncv[4];
  #pragma unroll
  for (int nt = 0; nt < 4; ++nt) ncv[nt] = norm_cent[bn0 + wn + nt * 16 + sub];

  #pragma unroll
  for (int mt = 0; mt < 4; ++mt) {
    #pragma unroll
    for (int r = 0; r < 4; ++r) {
      const int m = bm0 + wm + mt * 16 + q * 4 + r;
      const float nr = norm_rep[m];
      unsigned long long best = ~0ull;
      #pragma unroll
      for (int nt = 0; nt < 4; ++nt) {
        const int n = bn0 + wn + nt * 16 + sub;
        float d = (nr + ncv[nt]) - 2.0f * acc[mt][nt][r];
        unsigned long long p =
            ((unsigned long long)sortable_bits(d) << 32) | (unsigned int)n;
        if (p < best) best = p;
      }
      #pragma unroll
      for (int off = 1; off < 16; off <<= 1) {
        unsigned long long o =
            (unsigned long long)__shfl_xor((long long)best, off, 64);
        if (o < best) best = o;
      }
      if (sub == 0) atomicMin(&packed[m], best);
    }
  }
}

__global__ __launch_bounds__(192) void gather_kernel(
    const unsigned long long* __restrict__ packed,
    const float* __restrict__ cent,
    float* __restrict__ out_tokens, float* __restrict__ out_q) {
  int t = blockIdx.x;
  unsigned int k = (unsigned int)(packed[t] & 0xFFFFFFFFull);
  if (threadIdx.x == 0) out_tokens[t] = (float)k;
  const float4* src = (const float4*)(cent + (size_t)k * DD);
  float4* dst = (float4*)(out_q + (size_t)t * DD);
  dst[threadIdx.x] = src[threadIdx.x];
}

// ------- fallback path C: fp32 vector GEMM + argmin -------
#define FBM 64
#define FBN 64
#define FBK 16
#define FNSPLIT 16
__global__ __launch_bounds__(256) void fp32_argmin_gemm(
    const float* __restrict__ rep, const float* __restrict__ cent,
    const float* __restrict__ norm_rep, const float* __restrict__ norm_cent,
    unsigned long long* __restrict__ packed) {
  __shared__ float Asf[FBK][FBM];
  __shared__ float Bsf[FBK][FBN];
  const int tid = threadIdx.x;
  const int m0  = blockIdx.x * FBM;
  const int kbase = blockIdx.y * (KC / FNSPLIT);
  const int tx = tid & 15, ty = tid >> 4;
  const int ldr = tid >> 2, ldc = (tid & 3) * 4;
  const int t_ld = m0 + ldr;
  const float* arow =
      rep + (size_t)((t_ld >> 9) * T_STRIDE + 1 + (t_ld & 511)) * DD + ldc;
  unsigned long long best[4];
  #pragma unroll
  for (int i = 0; i < 4; ++i) best[i] = ~0ull;
  float nr[4];
  #pragma unroll
  for (int i = 0; i < 4; ++i) nr[i] = norm_rep[m0 + ty * 4 + i];
  for (int nt = 0; nt < (KC / FNSPLIT) / FBN; ++nt) {
    const int n0 = kbase + nt * FBN;
    const float* brow = cent + (size_t)(n0 + ldr) * DD + ldc;
    float acc[4][4];
    #pragma unroll
    for (int i = 0; i < 4; ++i)
      #pragma unroll
      for (int j = 0; j < 4; ++j) acc[i][j] = 0.f;
    for (int d0 = 0; d0 < DD; d0 += FBK) {
      float4 av = *(const float4*)(arow + d0);
      float4 bv = *(const float4*)(brow + d0);
      __syncthreads();
      Asf[ldc + 0][ldr] = av.x; Asf[ldc + 1][ldr] = av.y;
      Asf[ldc + 2][ldr] = av.z; Asf[ldc + 3][ldr] = av.w;
      Bsf[ldc + 0][ldr] = bv.x; Bsf[ldc + 1][ldr] = bv.y;
      Bsf[ldc + 2][ldr] = bv.z; Bsf[ldc + 3][ldr] = bv.w;
      __syncthreads();
      #pragma unroll
      for (int kk = 0; kk < FBK; ++kk) {
        float4 a4 = *(const float4*)&Asf[kk][ty * 4];
        float4 b4 = *(const float4*)&Bsf[kk][tx * 4];
        float a[4] = {a4.x, a4.y, a4.z, a4.w};
        float b[4] = {b4.x, b4.y, b4.z, b4.w};
        #pragma unroll
        for (int i = 0; i < 4; ++i)
          #pragma unroll
          for (int j = 0; j < 4; ++j) acc[i][j] += a[i] * b[j];
      }
    }
    #pragma unroll
    for (int i = 0; i < 4; ++i) {
      #pragma unroll
      for (int j = 0; j < 4; ++j) {
        int k = n0 + tx * 4 + j;
        float d = (nr[i] + norm_cent[k]) - 2.0f * acc[i][j];
        unsigned long long p =
            ((unsigned long long)sortable_bits(d) << 32) | (unsigned int)k;
        if (p < best[i]) best[i] = p;
      }
    }
  }
  #pragma unroll
  for (int off = 1; off < 16; off <<= 1) {
    #pragma unroll
    for (int i = 0; i < 4; ++i) {
      unsigned long long o =
          (unsigned long long)__shfl_xor((long long)best[i], off, 64);
      if (o < best[i]) best[i] = o;
    }
  }
  if (tx == 0) {
    #pragma unroll
    for (int i = 0; i < 4; ++i)
      atomicMin(&packed[m0 + ty * 4 + i], best[i]);
  }
}

extern "C" void kernel_launch(void* const* d_in, const int* in_sizes, int n_in,
                              void* d_out, int out_size, void* d_ws, size_t ws_size,
                              hipStream_t stream) {
  const float* rep  = (const float*)d_in[0];   // (8,513,768) fp32
  const float* cent = (const float*)d_in[1];   // (8192,768) fp32
  float* out = (float*)d_out;                  // [tokens(4096) | quantized(4096*768)]

  // path A layout: D | a_hi | b_hi | norms
  const size_t SZ_D   = (size_t)BT * KC * 2;        // 67,108,864
  const size_t SZ_AH  = (size_t)BT * DD * 2;        //  6,291,456
  const size_t SZ_BH  = (size_t)KC * DD * 2;        // 12,582,912
  const size_t WS_A = SZ_D + SZ_AH + SZ_BH + 49152;

  // path B layout (round-3): packed | norms | a_hi a_lo b_hi b_lo
  const size_t WS_B = 81920ull + 2 * 6291456ull + 2 * 12582912ull;

  if (ws_size >= WS_A) {
    _Float16* D    = (_Float16*)d_ws;
    _Float16* a_hi = (_Float16*)((char*)d_ws + SZ_D);
    _Float16* b_hi = (_Float16*)((char*)d_ws + SZ_D + SZ_AH);
    float* norm_rep  = (float*)((char*)d_ws + SZ_D + SZ_AH + SZ_BH);
    float* norm_cent = (float*)((char*)d_ws + SZ_D + SZ_AH + SZ_BH + 16384);

    split_norm_kernel<<<3072, 256, 0, stream>>>(
        rep, cent, a_hi, nullptr, b_hi, nullptr, norm_rep, norm_cent);
    dim3 grid(BT / 128, KC / 128);
    mfma_dist<<<grid, 256, 0, stream>>>(a_hi, b_hi, norm_rep, norm_cent, D);
    refine_kernel<<<BT, 256, 0, stream>>>(D, rep, cent, norm_rep, norm_cent,
                                          out, out + BT);
  } else if (ws_size >= WS_B) {
    unsigned long long* packed = (unsigned long long*)d_ws;
    float* norm_rep  = (float*)((char*)d_ws + 32768);
    float* norm_cent = (float*)((char*)d_ws + 49152);
    _Float16* a_hi = (_Float16*)((char*)d_ws + 81920);
    _Float16* a_lo = (_Float16*)((char*)d_ws + 81920 + 6291456);
    _Float16* b_hi = (_Float16*)((char*)d_ws + 81920 + 2 * 6291456);
    _Float16* b_lo = (_Float16*)((char*)d_ws + 81920 + 2 * 6291456 + 12582912);

    hipMemsetAsync(packed, 0xFF, BT * sizeof(unsigned long long), stream);
    split_norm_kernel<<<3072, 256, 0, stream>>>(
        rep, cent, a_hi, a_lo, b_hi, b_lo, norm_rep, norm_cent);
    dim3 grid(BT / 128, KC / 128);
    mfma_argmin<<<grid, 256, 0, stream>>>(a_hi, a_lo, b_hi, b_lo,
                                          norm_rep, norm_cent, packed);
    gather_kernel<<<BT, 192, 0, stream>>>(packed, cent, out, out + BT);
  } else {
    unsigned long long* packed = (unsigned long long*)d_ws;
    float* norm_rep  = (float*)((char*)d_ws + 32768);
    float* norm_cent = (float*)((char*)d_ws + 49152);

    hipMemsetAsync(packed, 0xFF, BT * sizeof(unsigned long long), stream);
    split_norm_kernel<<<3072, 256, 0, stream>>>(
        rep, cent, nullptr, nullptr, nullptr, nullptr, norm_rep, norm_cent);
    dim3 grid(BT / FBM, FNSPLIT);
    fp32_argmin_gemm<<<grid, 256, 0, stream>>>(rep, cent, norm_rep, norm_cent,
                                               packed);
    gather_kernel<<<BT, 192, 0, stream>>>(packed, cent, out, out + BT);
  }
}

// Round 5
// 173.681 us; speedup vs baseline: 4.8054x; 1.0037x over previous
//
#include <hip/hip_runtime.h>
#include <stdint.h>

#define BT 4096      // tokens total (8*512)
#define KC 8192      // centroids
#define DD 768       // feature dim
#define T_STRIDE 513 // rep row stride (skip token 0 per batch)
#define DELTA 6.0f   // candidate window; worst-case approx error chain <= 2.4

typedef _Float16 f16x8 __attribute__((ext_vector_type(8)));
typedef float    f32x4 __attribute__((ext_vector_type(4)));

#define GLD16(gp, lp)                                                       \
  __builtin_amdgcn_global_load_lds(                                         \
      (__attribute__((address_space(1))) void*)(gp),                        \
      (__attribute__((address_space(3))) void*)(lp), 16, 0, 0)

__device__ __forceinline__ unsigned int sortable_bits(float d) {
  unsigned int bits = __float_as_uint(d);
  return (bits & 0x80000000u) ? ~bits : (bits | 0x80000000u);
}

// ------- kernel 0: split fp32 -> fp16 hi + exact fp32 norms -------
__global__ __launch_bounds__(256) void split_norm_kernel(
    const float* __restrict__ rep, const float* __restrict__ cent,
    _Float16* __restrict__ a_hi, _Float16* __restrict__ b_hi,
    float* __restrict__ norm_rep, float* __restrict__ norm_cent) {
  int wid  = (blockIdx.x * blockDim.x + threadIdx.x) >> 6;
  int lane = threadIdx.x & 63;
  const float* src;
  _Float16* hi;
  float* nd;
  if (wid < BT) {
    int b = wid >> 9, tt = wid & 511;
    src = rep + (size_t)(b * T_STRIDE + 1 + tt) * DD;
    hi = a_hi ? a_hi + (size_t)wid * DD : nullptr;
    nd = norm_rep + wid;
  } else {
    int k = wid - BT;
    if (k >= KC) return;
    src = cent + (size_t)k * DD;
    hi = b_hi ? b_hi + (size_t)k * DD : nullptr;
    nd = norm_cent + k;
  }
  float s = 0.f;
  #pragma unroll
  for (int jj = 0; jj < DD / 64; ++jj) {
    int j = jj * 64 + lane;
    float v = src[j];
    s += v * v;
    if (hi) hi[j] = (_Float16)v;   // RTN
  }
  #pragma unroll
  for (int off = 32; off; off >>= 1) s += __shfl_down(s, off, 64);
  if (lane == 0) *nd = s;
}

// ------- kernel 1: hi.hi MFMA GEMM (K=768) -> per-(row, col-half) lmin + mask -------
// grid: (BT/128, KC/128) = (32, 64); 256 threads (4 waves, 2x2 of 64x64)
// LMin[m][h]: approx local min over the 64 cols of half h (h = 0..127)
// Mask[m][h]: bit b set iff d~(h*64+b) <= LMin[m][h] + DELTA  (superset of global cands)
__global__ __launch_bounds__(256, 2) void mfma_dist_cand(
    const _Float16* __restrict__ a_hi, const _Float16* __restrict__ b_hi,
    const float* __restrict__ norm_rep, const float* __restrict__ norm_cent,
    float* __restrict__ LMin, unsigned long long* __restrict__ Mask) {
  __shared__ _Float16 As[128 * 32];
  __shared__ _Float16 Bs[128 * 32];

  const int tid = threadIdx.x;
  const int w = tid >> 6, l = tid & 63;
  const int bm0 = blockIdx.x * 128;
  const int bn0 = blockIdx.y * 128;

  const int srow = l >> 2;
  const int scol = (l & 3) * 8;
  const size_t offA0 = (size_t)(bm0 + (w * 2 + 0) * 16 + srow) * DD + scol;
  const size_t offA1 = (size_t)(bm0 + (w * 2 + 1) * 16 + srow) * DD + scol;
  const size_t offB0 = (size_t)(bn0 + (w * 2 + 0) * 16 + srow) * DD + scol;
  const size_t offB1 = (size_t)(bn0 + (w * 2 + 1) * 16 + srow) * DD + scol;
  _Float16* ldsA0 = As + (w * 2 + 0) * 512;
  _Float16* ldsA1 = As + (w * 2 + 1) * 512;
  _Float16* ldsB0 = Bs + (w * 2 + 0) * 512;
  _Float16* ldsB1 = Bs + (w * 2 + 1) * 512;

  const int wm = (w & 1) * 64, wn = (w >> 1) * 64;
  const int sub = l & 15, q = l >> 4;
  const int aoff = (wm + sub) * 32 + q * 8;
  const int boff = (wn + sub) * 32 + q * 8;

  f32x4 acc[4][4] = {};

  for (int kin = 0; kin < DD; kin += 32) {
    __syncthreads();
    GLD16(a_hi + offA0 + kin, ldsA0);
    GLD16(a_hi + offA1 + kin, ldsA1);
    GLD16(b_hi + offB0 + kin, ldsB0);
    GLD16(b_hi + offB1 + kin, ldsB1);
    __syncthreads();

    f16x8 af[4], bfr[4];
    #pragma unroll
    for (int i = 0; i < 4; ++i) {
      af[i]  = *(const f16x8*)(As + aoff + i * 16 * 32);
      bfr[i] = *(const f16x8*)(Bs + boff + i * 16 * 32);
    }
    #pragma unroll
    for (int mt = 0; mt < 4; ++mt)
      #pragma unroll
      for (int nt = 0; nt < 4; ++nt)
        acc[mt][nt] = __builtin_amdgcn_mfma_f32_16x16x32_f16(
            af[mt], bfr[nt], acc[mt][nt], 0, 0, 0);
  }

  // epilogue: this wave covers rows [bm0+wm, +64) x cols [bn0+wn, +64)
  const int halfidx = blockIdx.y * 2 + (w >> 1);   // global 64-col half index
  float ncv[4];
  #pragma unroll
  for (int nt = 0; nt < 4; ++nt) ncv[nt] = norm_cent[bn0 + wn + nt * 16 + sub];

  #pragma unroll
  for (int mt = 0; mt < 4; ++mt) {
    #pragma unroll
    for (int r = 0; r < 4; ++r) {
      const int m = bm0 + wm + mt * 16 + q * 4 + r;
      const float nr = norm_rep[m];
      float d[4], mymin;
      #pragma unroll
      for (int nt = 0; nt < 4; ++nt)
        d[nt] = (nr + ncv[nt]) - 2.0f * acc[mt][nt][r];
      mymin = fminf(fminf(d[0], d[1]), fminf(d[2], d[3]));
      // min over the 16 sub lanes of this q-group
      #pragma unroll
      for (int off = 1; off < 16; off <<= 1)
        mymin = fminf(mymin, __shfl_xor(mymin, off, 64));
      const float thresh = mymin + DELTA;
      unsigned long long half = 0;
      #pragma unroll
      for (int nt = 0; nt < 4; ++nt) {
        unsigned long long b = __ballot(d[nt] <= thresh);
        half |= ((b >> (q * 16)) & 0xFFFFull) << (nt * 16);
      }
      if (sub == 0) {
        LMin[(size_t)m * 128 + halfidx] = mymin;
        Mask[(size_t)m * 128 + halfidx] = half;
      }
    }
  }
}

// ------- kernel 2: per-token refine (global min over halves + exact recheck) -------
__global__ __launch_bounds__(256) void refine_kernel(
    const float* __restrict__ LMin, const unsigned long long* __restrict__ Mask,
    const float* __restrict__ rep, const float* __restrict__ cent,
    const float* __restrict__ norm_rep, const float* __restrict__ norm_cent,
    float* __restrict__ out_tokens, float* __restrict__ out_q) {
  __shared__ float s_min[4];
  __shared__ float s_red[4];
  __shared__ int s_half[128];
  __shared__ int s_cnt;
  __shared__ int s_kbest;

  const int t = blockIdx.x;
  const int tid = threadIdx.x;
  const int w = tid >> 6, l = tid & 63;

  if (tid == 0) s_cnt = 0;
  float lm = (tid < 128) ? LMin[(size_t)t * 128 + tid] : 3.4e38f;
  float v = lm;
  #pragma unroll
  for (int off = 32; off; off >>= 1) v = fminf(v, __shfl_xor(v, off, 64));
  if (l == 0) s_min[w] = v;
  __syncthreads();
  const float gmin = fminf(fminf(s_min[0], s_min[1]), fminf(s_min[2], s_min[3]));
  const float thresh = gmin + DELTA;
  if (tid < 128 && lm <= thresh) {
    int idx = atomicAdd(&s_cnt, 1);
    s_half[idx] = tid;
  }
  __syncthreads();
  const int cnt = s_cnt;

  const int b_ = t >> 9, tt = t & 511;
  const float* rrow = rep + (size_t)(b_ * T_STRIDE + 1 + tt) * DD;
  const float nr = norm_rep[t];
  unsigned long long bestE = ~0ull;

  for (int c = 0; c < cnt; ++c) {
    const int h = s_half[c];
    unsigned long long mask = Mask[(size_t)t * 128 + h];  // uniform across block
    while (mask) {
      const int bit = __ffsll((unsigned long long)mask) - 1;
      mask &= mask - 1;
      const int k = h * 64 + bit;
      const float* crow = cent + (size_t)k * DD;
      float part = 0.f;
      #pragma unroll
      for (int j = 0; j < 3; ++j)
        part += rrow[tid + j * 256] * crow[tid + j * 256];
      #pragma unroll
      for (int off = 32; off; off >>= 1) part += __shfl_down(part, off, 64);
      if (l == 0) s_red[w] = part;
      __syncthreads();
      if (tid == 0) {
        float dot = s_red[0] + s_red[1] + s_red[2] + s_red[3];
        float d = (nr + norm_cent[k]) - 2.0f * dot;
        unsigned long long p =
            ((unsigned long long)sortable_bits(d) << 32) | (unsigned)k;
        if (p < bestE) bestE = p;
      }
      __syncthreads();
    }
  }
  if (tid == 0) {
    s_kbest = (int)(bestE & 0xFFFFFFFFull);
    out_tokens[t] = (float)s_kbest;
  }
  __syncthreads();
  const int kbest = s_kbest;
  if (tid < 192) {
    const float4* src = (const float4*)(cent + (size_t)kbest * DD);
    float4* dst = (float4*)(out_q + (size_t)t * DD);
    dst[tid] = src[tid];
  }
}

// ------- fallback: fp32 vector GEMM + argmin (tiny ws) -------
#define FBM 64
#define FBN 64
#define FBK 16
#define FNSPLIT 16
__global__ __launch_bounds__(256) void fp32_argmin_gemm(
    const float* __restrict__ rep, const float* __restrict__ cent,
    const float* __restrict__ norm_rep, const float* __restrict__ norm_cent,
    unsigned long long* __restrict__ packed) {
  __shared__ float Asf[FBK][FBM];
  __shared__ float Bsf[FBK][FBN];
  const int tid = threadIdx.x;
  const int m0  = blockIdx.x * FBM;
  const int kbase = blockIdx.y * (KC / FNSPLIT);
  const int tx = tid & 15, ty = tid >> 4;
  const int ldr = tid >> 2, ldc = (tid & 3) * 4;
  const int t_ld = m0 + ldr;
  const float* arow =
      rep + (size_t)((t_ld >> 9) * T_STRIDE + 1 + (t_ld & 511)) * DD + ldc;
  unsigned long long best[4];
  #pragma unroll
  for (int i = 0; i < 4; ++i) best[i] = ~0ull;
  float nr[4];
  #pragma unroll
  for (int i = 0; i < 4; ++i) nr[i] = norm_rep[m0 + ty * 4 + i];
  for (int nt = 0; nt < (KC / FNSPLIT) / FBN; ++nt) {
    const int n0 = kbase + nt * FBN;
    const float* brow = cent + (size_t)(n0 + ldr) * DD + ldc;
    float acc[4][4];
    #pragma unroll
    for (int i = 0; i < 4; ++i)
      #pragma unroll
      for (int j = 0; j < 4; ++j) acc[i][j] = 0.f;
    for (int d0 = 0; d0 < DD; d0 += FBK) {
      float4 av = *(const float4*)(arow + d0);
      float4 bv = *(const float4*)(brow + d0);
      __syncthreads();
      Asf[ldc + 0][ldr] = av.x; Asf[ldc + 1][ldr] = av.y;
      Asf[ldc + 2][ldr] = av.z; Asf[ldc + 3][ldr] = av.w;
      Bsf[ldc + 0][ldr] = bv.x; Bsf[ldc + 1][ldr] = bv.y;
      Bsf[ldc + 2][ldr] = bv.z; Bsf[ldc + 3][ldr] = bv.w;
      __syncthreads();
      #pragma unroll
      for (int kk = 0; kk < FBK; ++kk) {
        float4 a4 = *(const float4*)&Asf[kk][ty * 4];
        float4 b4 = *(const float4*)&Bsf[kk][tx * 4];
        float a[4] = {a4.x, a4.y, a4.z, a4.w};
        float b[4] = {b4.x, b4.y, b4.z, b4.w};
        #pragma unroll
        for (int i = 0; i < 4; ++i)
          #pragma unroll
          for (int j = 0; j < 4; ++j) acc[i][j] += a[i] * b[j];
      }
    }
    #pragma unroll
    for (int i = 0; i < 4; ++i) {
      #pragma unroll
      for (int j = 0; j < 4; ++j) {
        int k = n0 + tx * 4 + j;
        float d = (nr[i] + norm_cent[k]) - 2.0f * acc[i][j];
        unsigned long long p =
            ((unsigned long long)sortable_bits(d) << 32) | (unsigned int)k;
        if (p < best[i]) best[i] = p;
      }
    }
  }
  #pragma unroll
  for (int off = 1; off < 16; off <<= 1) {
    #pragma unroll
    for (int i = 0; i < 4; ++i) {
      unsigned long long o =
          (unsigned long long)__shfl_xor((long long)best[i], off, 64);
      if (o < best[i]) best[i] = o;
    }
  }
  if (tx == 0) {
    #pragma unroll
    for (int i = 0; i < 4; ++i)
      atomicMin(&packed[m0 + ty * 4 + i], best[i]);
  }
}

__global__ __launch_bounds__(192) void gather_kernel(
    const unsigned long long* __restrict__ packed,
    const float* __restrict__ cent,
    float* __restrict__ out_tokens, float* __restrict__ out_q) {
  int t = blockIdx.x;
  unsigned int k = (unsigned int)(packed[t] & 0xFFFFFFFFull);
  if (threadIdx.x == 0) out_tokens[t] = (float)k;
  const float4* src = (const float4*)(cent + (size_t)k * DD);
  float4* dst = (float4*)(out_q + (size_t)t * DD);
  dst[threadIdx.x] = src[threadIdx.x];
}

extern "C" void kernel_launch(void* const* d_in, const int* in_sizes, int n_in,
                              void* d_out, int out_size, void* d_ws, size_t ws_size,
                              hipStream_t stream) {
  const float* rep  = (const float*)d_in[0];   // (8,513,768) fp32
  const float* cent = (const float*)d_in[1];   // (8192,768) fp32
  float* out = (float*)d_out;                  // [tokens(4096) | quantized(4096*768)]

  // path A layout: a_hi | b_hi | LMin | Mask | norms
  const size_t SZ_AH = (size_t)BT * DD * 2;          //  6 MiB
  const size_t SZ_BH = (size_t)KC * DD * 2;          // 12 MiB
  const size_t SZ_LM = (size_t)BT * 128 * 4;         //  2 MiB
  const size_t SZ_MK = (size_t)BT * 128 * 8;         //  4 MiB
  const size_t WS_A  = SZ_AH + SZ_BH + SZ_LM + SZ_MK + 49152;

  if (ws_size >= WS_A) {
    _Float16* a_hi = (_Float16*)d_ws;
    _Float16* b_hi = (_Float16*)((char*)d_ws + SZ_AH);
    float* LMin    = (float*)((char*)d_ws + SZ_AH + SZ_BH);
    unsigned long long* Mask =
        (unsigned long long*)((char*)d_ws + SZ_AH + SZ_BH + SZ_LM);
    float* norm_rep  = (float*)((char*)d_ws + SZ_AH + SZ_BH + SZ_LM + SZ_MK);
    float* norm_cent = (float*)((char*)d_ws + SZ_AH + SZ_BH + SZ_LM + SZ_MK + 16384);

    split_norm_kernel<<<3072, 256, 0, stream>>>(rep, cent, a_hi, b_hi,
                                                norm_rep, norm_cent);
    dim3 grid(BT / 128, KC / 128);
    mfma_dist_cand<<<grid, 256, 0, stream>>>(a_hi, b_hi, norm_rep, norm_cent,
                                             LMin, Mask);
    refine_kernel<<<BT, 256, 0, stream>>>(LMin, Mask, rep, cent, norm_rep,
                                          norm_cent, out, out + BT);
  } else {
    unsigned long long* packed = (unsigned long long*)d_ws;
    float* norm_rep  = (float*)((char*)d_ws + 32768);
    float* norm_cent = (float*)((char*)d_ws + 49152);

    hipMemsetAsync(packed, 0xFF, BT * sizeof(unsigned long long), stream);
    split_norm_kernel<<<3072, 256, 0, stream>>>(rep, cent, nullptr, nullptr,
                                                norm_rep, norm_cent);
    dim3 grid(BT / FBM, FNSPLIT);
    fp32_argmin_gemm<<<grid, 256, 0, stream>>>(rep, cent, norm_rep, norm_cent,
                                               packed);
    gather_kernel<<<BT, 192, 0, stream>>>(packed, cent, out, out + BT);
  }
}

// Round 6
// 146.134 us; speedup vs baseline: 5.7113x; 1.1885x over previous
//
#include <hip/hip_runtime.h>
#include <stdint.h>

#define BT 4096      // tokens total (8*512)
#define KC 8192      // centroids
#define DD 768       // feature dim
#define T_STRIDE 513 // rep row stride (skip token 0 per batch)
#define DELTA 6.0f   // candidate window; worst-case fp16 approx error chain <= 2.4

typedef _Float16 f16x8 __attribute__((ext_vector_type(8)));
typedef _Float16 f16x4 __attribute__((ext_vector_type(4)));
typedef float    f32x4 __attribute__((ext_vector_type(4)));

#define GLD16(gp, lp)                                                       \
  __builtin_amdgcn_global_load_lds(                                         \
      (__attribute__((address_space(1))) void*)(gp),                        \
      (__attribute__((address_space(3))) void*)(lp), 16, 0, 0)

__device__ __forceinline__ unsigned int sortable_bits(float d) {
  unsigned int bits = __float_as_uint(d);
  return (bits & 0x80000000u) ? ~bits : (bits | 0x80000000u);
}

// ------- kernel 0: split fp32 -> fp16 hi + exact fp32 norms (vectorized) -------
__global__ __launch_bounds__(256) void split_norm_kernel(
    const float* __restrict__ rep, const float* __restrict__ cent,
    _Float16* __restrict__ a_hi, _Float16* __restrict__ b_hi,
    float* __restrict__ norm_rep, float* __restrict__ norm_cent) {
  int wid  = (blockIdx.x * blockDim.x + threadIdx.x) >> 6;
  int lane = threadIdx.x & 63;
  const float* src;
  _Float16* hi;
  float* nd;
  if (wid < BT) {
    int b = wid >> 9, tt = wid & 511;
    src = rep + (size_t)(b * T_STRIDE + 1 + tt) * DD;
    hi = a_hi ? a_hi + (size_t)wid * DD : nullptr;
    nd = norm_rep + wid;
  } else {
    int k = wid - BT;
    if (k >= KC) return;
    src = cent + (size_t)k * DD;
    hi = b_hi ? b_hi + (size_t)k * DD : nullptr;
    nd = norm_cent + k;
  }
  const float4* s4 = (const float4*)src;
  f16x4* h4 = (f16x4*)hi;
  float s = 0.f;
  #pragma unroll
  for (int i = 0; i < 3; ++i) {   // 3 * 64 lanes * 4 floats = 768
    float4 v = s4[lane + i * 64];
    s += v.x * v.x + v.y * v.y + v.z * v.z + v.w * v.w;
    if (hi) {
      f16x4 h;
      h[0] = (_Float16)v.x; h[1] = (_Float16)v.y;
      h[2] = (_Float16)v.z; h[3] = (_Float16)v.w;
      h4[lane + i * 64] = h;
    }
  }
  #pragma unroll
  for (int off = 32; off; off >>= 1) s += __shfl_down(s, off, 64);
  if (lane == 0) *nd = s;
}

// ------- kernel 1: hi.hi MFMA GEMM, A=centroids B=tokens, BK=64 swizzled -------
// grid: (KC/128, BT/128) = (64, 32); 256 threads (4 waves, 2x2 of 64x64)
// Per token t and 64-centroid group g: LMin[t][g] (approx local min) and
// Mask[t][g] (bit b set iff d~(g*64+b) <= LMin+DELTA) — superset of true cands.
__global__ __launch_bounds__(256, 2) void mfma_dist_cand(
    const _Float16* __restrict__ a_hi,   // tokens  [BT][DD]
    const _Float16* __restrict__ b_hi,   // cents   [KC][DD]
    const float* __restrict__ norm_rep, const float* __restrict__ norm_cent,
    float* __restrict__ LMin, unsigned long long* __restrict__ Mask) {
  __shared__ _Float16 As[128 * 64];  // centroid tile (rows = cents)
  __shared__ _Float16 Bs[128 * 64];  // token tile    (rows = tokens)

  const int tid = threadIdx.x;
  const int w = tid >> 6, l = tid & 63;
  const int bm0 = blockIdx.x * 128;  // centroid base
  const int bn0 = blockIdx.y * 128;  // token base

  // staging: instr j covers 8 rows x 128B; lane l -> row j*8+(l>>3),
  // global chunk c = (l&7) ^ (l>>3)  (XOR swizzle; LDS dest stays lane*16B)
  const int srow   = l >> 3;
  const int schunk = (l & 7) ^ srow;
  size_t goffA[4], goffB[4];
  _Float16 *ldsA[4], *ldsB[4];
  #pragma unroll
  for (int j2 = 0; j2 < 4; ++j2) {
    const int j = w * 4 + j2;
    goffA[j2] = (size_t)(bm0 + j * 8 + srow) * DD + schunk * 8;
    goffB[j2] = (size_t)(bn0 + j * 8 + srow) * DD + schunk * 8;
    ldsA[j2] = As + j * 8 * 64;
    ldsB[j2] = Bs + j * 8 * 64;
  }

  const int wm = (w & 1) * 64;   // centroid offset within tile
  const int wn = (w >> 1) * 64;  // token offset within tile
  const int sub = l & 15, q = l >> 4;

  f32x4 acc[4][4] = {};  // [mt: cent subtile][nt: token subtile]

  for (int kin = 0; kin < DD; kin += 64) {
    __syncthreads();   // previous frag reads done before overwrite
    #pragma unroll
    for (int j2 = 0; j2 < 4; ++j2) {
      GLD16(b_hi + goffA[j2] + kin, ldsA[j2]);
      GLD16(a_hi + goffB[j2] + kin, ldsB[j2]);
    }
    __syncthreads();   // drain vmcnt -> LDS visible

    #pragma unroll
    for (int kk = 0; kk < 2; ++kk) {
      f16x8 af[4], bfr[4];
      #pragma unroll
      for (int i = 0; i < 4; ++i) {
        const int arow = wm + i * 16 + sub;
        const int brow = wn + i * 16 + sub;
        const int c = q + kk * 4;   // logical chunk for k = kk*32 + q*8
        af[i]  = *(const f16x8*)(As + arow * 64 + ((c ^ (arow & 7)) * 8));
        bfr[i] = *(const f16x8*)(Bs + brow * 64 + ((c ^ (brow & 7)) * 8));
      }
      #pragma unroll
      for (int mt = 0; mt < 4; ++mt)
        #pragma unroll
        for (int nt = 0; nt < 4; ++nt)
          acc[mt][nt] = __builtin_amdgcn_mfma_f32_16x16x32_f16(
              af[mt], bfr[nt], acc[mt][nt], 0, 0, 0);
    }
  }

  // epilogue: per lane, 16 distances of token (nt,sub) are IN-LANE (mt x r)
  const int g = blockIdx.x * 2 + (w & 1);   // 64-centroid group index
  float ncv[4][4];
  #pragma unroll
  for (int mt = 0; mt < 4; ++mt)
    #pragma unroll
    for (int r = 0; r < 4; ++r)
      ncv[mt][r] = norm_cent[bm0 + wm + mt * 16 + q * 4 + r];

  #pragma unroll
  for (int nt = 0; nt < 4; ++nt) {
    const int t = bn0 + wn + nt * 16 + sub;
    const float nr = norm_rep[t];
    float d[4][4];
    float dmin = 3.4e38f;
    #pragma unroll
    for (int mt = 0; mt < 4; ++mt)
      #pragma unroll
      for (int r = 0; r < 4; ++r) {
        d[mt][r] = (nr + ncv[mt][r]) - 2.0f * acc[mt][nt][r];
        dmin = fminf(dmin, d[mt][r]);
      }
    // fold across the 4 q-lanes holding this token (lanes differ in bits 4..5)
    dmin = fminf(dmin, __shfl_xor(dmin, 16, 64));
    dmin = fminf(dmin, __shfl_xor(dmin, 32, 64));
    const float thresh = dmin + DELTA;
    unsigned long long pm = 0;
    #pragma unroll
    for (int mt = 0; mt < 4; ++mt)
      #pragma unroll
      for (int r = 0; r < 4; ++r)
        if (d[mt][r] <= thresh) pm |= 1ull << (mt * 16 + q * 4 + r);
    pm |= (unsigned long long)__shfl_xor((long long)pm, 16, 64);
    pm |= (unsigned long long)__shfl_xor((long long)pm, 32, 64);
    if (q == 0) {
      LMin[(size_t)t * 128 + g] = dmin;
      Mask[(size_t)t * 128 + g] = pm;
    }
  }
}

// ------- kernel 2: per-token refine (wave-parallel exact recheck) -------
__global__ __launch_bounds__(256) void refine_kernel(
    const float* __restrict__ LMin, const unsigned long long* __restrict__ Mask,
    const float* __restrict__ rep, const float* __restrict__ cent,
    const float* __restrict__ norm_rep, const float* __restrict__ norm_cent,
    float* __restrict__ out_tokens, float* __restrict__ out_q) {
  __shared__ float s_min[4];
  __shared__ int s_half[128];
  __shared__ int s_cnt;
  __shared__ unsigned long long s_bestw[4];
  __shared__ int s_kbest;

  const int t = blockIdx.x;
  const int tid = threadIdx.x;
  const int w = tid >> 6, l = tid & 63;

  if (tid == 0) s_cnt = 0;
  float lm = (tid < 128) ? LMin[(size_t)t * 128 + tid] : 3.4e38f;
  float v = lm;
  #pragma unroll
  for (int off = 32; off; off >>= 1) v = fminf(v, __shfl_xor(v, off, 64));
  if (l == 0) s_min[w] = v;
  __syncthreads();
  const float gmin = fminf(fminf(s_min[0], s_min[1]), fminf(s_min[2], s_min[3]));
  const float thresh = gmin + DELTA;
  if (tid < 128 && lm <= thresh) {
    int idx = atomicAdd(&s_cnt, 1);
    s_half[idx] = tid;
  }
  __syncthreads();
  const int cnt = s_cnt;

  const int b_ = t >> 9, tt = t & 511;
  const float* rrow = rep + (size_t)(b_ * T_STRIDE + 1 + tt) * DD;
  const float nr = norm_rep[t];
  unsigned long long bestE = ~0ull;
  int cno = 0;

  for (int c = 0; c < cnt; ++c) {
    const int h = s_half[c];
    unsigned long long mask = Mask[(size_t)t * 128 + h];
    while (mask) {
      const int bit = __ffsll((unsigned long long)mask) - 1;
      mask &= mask - 1;
      if ((cno++ & 3) == w) {            // round-robin candidates to waves
        const int k = h * 64 + bit;
        const float* crow = cent + (size_t)k * DD;
        float part = 0.f;
        #pragma unroll
        for (int j = 0; j < 12; ++j)
          part += rrow[l + j * 64] * crow[l + j * 64];
        #pragma unroll
        for (int off = 32; off; off >>= 1) part += __shfl_down(part, off, 64);
        if (l == 0) {
          float d = (nr + norm_cent[k]) - 2.0f * part;
          unsigned long long p =
              ((unsigned long long)sortable_bits(d) << 32) | (unsigned)k;
          if (p < bestE) bestE = p;
        }
      }
    }
  }
  if (l == 0) s_bestw[w] = bestE;
  __syncthreads();
  if (tid == 0) {
    unsigned long long b = s_bestw[0];
    #pragma unroll
    for (int i = 1; i < 4; ++i) if (s_bestw[i] < b) b = s_bestw[i];
    s_kbest = (int)(b & 0xFFFFFFFFull);
    out_tokens[t] = (float)s_kbest;
  }
  __syncthreads();
  const int kbest = s_kbest;
  if (tid < 192) {
    const float4* src = (const float4*)(cent + (size_t)kbest * DD);
    float4* dst = (float4*)(out_q + (size_t)t * DD);
    dst[tid] = src[tid];
  }
}

// ------- fallback: fp32 vector GEMM + argmin (tiny ws) -------
#define FBM 64
#define FBN 64
#define FBK 16
#define FNSPLIT 16
__global__ __launch_bounds__(256) void fp32_argmin_gemm(
    const float* __restrict__ rep, const float* __restrict__ cent,
    const float* __restrict__ norm_rep, const float* __restrict__ norm_cent,
    unsigned long long* __restrict__ packed) {
  __shared__ float Asf[FBK][FBM];
  __shared__ float Bsf[FBK][FBN];
  const int tid = threadIdx.x;
  const int m0  = blockIdx.x * FBM;
  const int kbase = blockIdx.y * (KC / FNSPLIT);
  const int tx = tid & 15, ty = tid >> 4;
  const int ldr = tid >> 2, ldc = (tid & 3) * 4;
  const int t_ld = m0 + ldr;
  const float* arow =
      rep + (size_t)((t_ld >> 9) * T_STRIDE + 1 + (t_ld & 511)) * DD + ldc;
  unsigned long long best[4];
  #pragma unroll
  for (int i = 0; i < 4; ++i) best[i] = ~0ull;
  float nr[4];
  #pragma unroll
  for (int i = 0; i < 4; ++i) nr[i] = norm_rep[m0 + ty * 4 + i];
  for (int nt = 0; nt < (KC / FNSPLIT) / FBN; ++nt) {
    const int n0 = kbase + nt * FBN;
    const float* brow = cent + (size_t)(n0 + ldr) * DD + ldc;
    float acc[4][4];
    #pragma unroll
    for (int i = 0; i < 4; ++i)
      #pragma unroll
      for (int j = 0; j < 4; ++j) acc[i][j] = 0.f;
    for (int d0 = 0; d0 < DD; d0 += FBK) {
      float4 av = *(const float4*)(arow + d0);
      float4 bv = *(const float4*)(brow + d0);
      __syncthreads();
      Asf[ldc + 0][ldr] = av.x; Asf[ldc + 1][ldr] = av.y;
      Asf[ldc + 2][ldr] = av.z; Asf[ldc + 3][ldr] = av.w;
      Bsf[ldc + 0][ldr] = bv.x; Bsf[ldc + 1][ldr] = bv.y;
      Bsf[ldc + 2][ldr] = bv.z; Bsf[ldc + 3][ldr] = bv.w;
      __syncthreads();
      #pragma unroll
      for (int kk = 0; kk < FBK; ++kk) {
        float4 a4 = *(const float4*)&Asf[kk][ty * 4];
        float4 b4 = *(const float4*)&Bsf[kk][tx * 4];
        float a[4] = {a4.x, a4.y, a4.z, a4.w};
        float b[4] = {b4.x, b4.y, b4.z, b4.w};
        #pragma unroll
        for (int i = 0; i < 4; ++i)
          #pragma unroll
          for (int j = 0; j < 4; ++j) acc[i][j] += a[i] * b[j];
      }
    }
    #pragma unroll
    for (int i = 0; i < 4; ++i) {
      #pragma unroll
      for (int j = 0; j < 4; ++j) {
        int k = n0 + tx * 4 + j;
        float d = (nr[i] + norm_cent[k]) - 2.0f * acc[i][j];
        unsigned long long p =
            ((unsigned long long)sortable_bits(d) << 32) | (unsigned int)k;
        if (p < best[i]) best[i] = p;
      }
    }
  }
  #pragma unroll
  for (int off = 1; off < 16; off <<= 1) {
    #pragma unroll
    for (int i = 0; i < 4; ++i) {
      unsigned long long o =
          (unsigned long long)__shfl_xor((long long)best[i], off, 64);
      if (o < best[i]) best[i] = o;
    }
  }
  if (tx == 0) {
    #pragma unroll
    for (int i = 0; i < 4; ++i)
      atomicMin(&packed[m0 + ty * 4 + i], best[i]);
  }
}

__global__ __launch_bounds__(192) void gather_kernel(
    const unsigned long long* __restrict__ packed,
    const float* __restrict__ cent,
    float* __restrict__ out_tokens, float* __restrict__ out_q) {
  int t = blockIdx.x;
  unsigned int k = (unsigned int)(packed[t] & 0xFFFFFFFFull);
  if (threadIdx.x == 0) out_tokens[t] = (float)k;
  const float4* src = (const float4*)(cent + (size_t)k * DD);
  float4* dst = (float4*)(out_q + (size_t)t * DD);
  dst[threadIdx.x] = src[threadIdx.x];
}

extern "C" void kernel_launch(void* const* d_in, const int* in_sizes, int n_in,
                              void* d_out, int out_size, void* d_ws, size_t ws_size,
                              hipStream_t stream) {
  const float* rep  = (const float*)d_in[0];   // (8,513,768) fp32
  const float* cent = (const float*)d_in[1];   // (8192,768) fp32
  float* out = (float*)d_out;                  // [tokens(4096) | quantized(4096*768)]

  // path A layout: a_hi | b_hi | LMin | Mask | norms
  const size_t SZ_AH = (size_t)BT * DD * 2;          //  6 MiB
  const size_t SZ_BH = (size_t)KC * DD * 2;          // 12 MiB
  const size_t SZ_LM = (size_t)BT * 128 * 4;         //  2 MiB
  const size_t SZ_MK = (size_t)BT * 128 * 8;         //  4 MiB
  const size_t WS_A  = SZ_AH + SZ_BH + SZ_LM + SZ_MK + 49152;

  if (ws_size >= WS_A) {
    _Float16* a_hi = (_Float16*)d_ws;
    _Float16* b_hi = (_Float16*)((char*)d_ws + SZ_AH);
    float* LMin    = (float*)((char*)d_ws + SZ_AH + SZ_BH);
    unsigned long long* Mask =
        (unsigned long long*)((char*)d_ws + SZ_AH + SZ_BH + SZ_LM);
    float* norm_rep  = (float*)((char*)d_ws + SZ_AH + SZ_BH + SZ_LM + SZ_MK);
    float* norm_cent = (float*)((char*)d_ws + SZ_AH + SZ_BH + SZ_LM + SZ_MK + 16384);

    split_norm_kernel<<<3072, 256, 0, stream>>>(rep, cent, a_hi, b_hi,
                                                norm_rep, norm_cent);
    dim3 grid(KC / 128, BT / 128);
    mfma_dist_cand<<<grid, 256, 0, stream>>>(a_hi, b_hi, norm_rep, norm_cent,
                                             LMin, Mask);
    refine_kernel<<<BT, 256, 0, stream>>>(LMin, Mask, rep, cent, norm_rep,
                                          norm_cent, out, out + BT);
  } else {
    unsigned long long* packed = (unsigned long long*)d_ws;
    float* norm_rep  = (float*)((char*)d_ws + 32768);
    float* norm_cent = (float*)((char*)d_ws + 49152);

    hipMemsetAsync(packed, 0xFF, BT * sizeof(unsigned long long), stream);
    split_norm_kernel<<<3072, 256, 0, stream>>>(rep, cent, nullptr, nullptr,
                                                norm_rep, norm_cent);
    dim3 grid(BT / FBM, FNSPLIT);
    fp32_argmin_gemm<<<grid, 256, 0, stream>>>(rep, cent, norm_rep, norm_cent,
                                               packed);
    gather_kernel<<<BT, 192, 0, stream>>>(packed, cent, out, out + BT);
  }
}